// Round 1
// baseline (538.996 us; speedup 1.0000x reference)
//
#include <hip/hip_runtime.h>
#include <cstddef>

// Problem constants
#define QSZ 2097152  // B*H*N*HD = 8*8*1024*32 floats (also = 8192*256)

// ---------------------------------------------------------------------------
// CPB MLP: table[h][r] = fc2(relu(fc1(rct[r]))) ; one thread per table row.
// ---------------------------------------------------------------------------
__global__ __launch_bounds__(256)
void cpb_kernel(const float* __restrict__ rct,
                const float* __restrict__ fc1w, const float* __restrict__ fc1b,
                const float* __restrict__ fc2w, const float* __restrict__ fc2b,
                float* __restrict__ table)
{
    int r = blockIdx.x * 256 + threadIdx.x;
    if (r >= 3969) return;
    float c0 = rct[2*r], c1 = rct[2*r+1];
    float acc[8] = {0,0,0,0,0,0,0,0};
    for (int j = 0; j < 512; ++j) {
        float hv = fmaxf(c0*fc1w[2*j] + c1*fc1w[2*j+1] + fc1b[j], 0.0f);
        #pragma unroll
        for (int hh = 0; hh < 8; ++hh) acc[hh] += hv * fc2w[hh*512 + j];
    }
    #pragma unroll
    for (int hh = 0; hh < 8; ++hh) table[hh*3969 + r] = acc[hh] + fc2b[hh];
}

// ---------------------------------------------------------------------------
// Tiled fp32 SGEMM, C[m][n] = sum_k A[m][k]*W[n][k] + bias[n]
// MODE 0: plain row-major C. MODE 1: scatter qkv channels into q/k/v [B,H,N,32].
// 64x64 tile, 256 threads, 4x4 microtile, BK=16.
// ---------------------------------------------------------------------------
template<int MODE>
__global__ __launch_bounds__(256)
void sgemm_bt(const float* __restrict__ A, const float* __restrict__ W,
              const float* __restrict__ bias, float* __restrict__ C,
              float* __restrict__ qb, float* __restrict__ kb, float* __restrict__ vb,
              int M, int N, int K)
{
    __shared__ __align__(16) float As[16][68];
    __shared__ __align__(16) float Bs[16][68];
    int tid = threadIdx.x;
    int tx = tid & 15, ty = tid >> 4;
    int m0 = blockIdx.y * 64, n0 = blockIdx.x * 64;
    int lm = tid >> 2;          // 0..63
    int lk = (tid & 3) * 4;     // 0,4,8,12
    float acc[4][4] = {};
    const float* Ap = A + (size_t)(m0 + lm) * K + lk;
    const float* Wp = W + (size_t)(n0 + lm) * K + lk;

    for (int k0 = 0; k0 < K; k0 += 16) {
        float4 a4 = *(const float4*)(Ap + k0);
        float4 w4 = *(const float4*)(Wp + k0);
        As[lk+0][lm]=a4.x; As[lk+1][lm]=a4.y; As[lk+2][lm]=a4.z; As[lk+3][lm]=a4.w;
        Bs[lk+0][lm]=w4.x; Bs[lk+1][lm]=w4.y; Bs[lk+2][lm]=w4.z; Bs[lk+3][lm]=w4.w;
        __syncthreads();
        #pragma unroll
        for (int kk = 0; kk < 16; ++kk) {
            float4 av = *(const float4*)&As[kk][ty*4];
            float4 bv = *(const float4*)&Bs[kk][tx*4];
            float aa[4] = {av.x, av.y, av.z, av.w};
            float bb[4] = {bv.x, bv.y, bv.z, bv.w};
            #pragma unroll
            for (int i = 0; i < 4; ++i)
                #pragma unroll
                for (int j = 0; j < 4; ++j)
                    acc[i][j] += aa[i] * bb[j];
        }
        __syncthreads();
    }

    if (MODE == 0) {
        #pragma unroll
        for (int i = 0; i < 4; ++i) {
            int m = m0 + ty*4 + i;
            int n = n0 + tx*4;
            float4 o;
            o.x = acc[i][0] + bias[n+0];
            o.y = acc[i][1] + bias[n+1];
            o.z = acc[i][2] + bias[n+2];
            o.w = acc[i][3] + bias[n+3];
            *(float4*)(C + (size_t)m*N + n) = o;
        }
    } else {
        // qkv scatter: channel n -> which=n/256 (q/k/v), head=(n%256)/32, d=n%32
        int n = n0 + tx*4;
        int which = n >> 8;
        int head  = (n >> 5) & 7;
        int dd    = n & 31;           // 4 consecutive d's, same head
        float* dst = (which == 0) ? qb : (which == 1) ? kb : vb;
        #pragma unroll
        for (int i = 0; i < 4; ++i) {
            int m = m0 + ty*4 + i;
            int bb = m >> 10, nrow = m & 1023;
            float4 o;
            o.x = acc[i][0] + bias[n+0];
            o.y = acc[i][1] + bias[n+1];
            o.z = acc[i][2] + bias[n+2];
            o.w = acc[i][3] + bias[n+3];
            *(float4*)(dst + (((size_t)bb*8 + head)*1024 + nrow)*32 + dd) = o;
        }
    }
}

// ---------------------------------------------------------------------------
// Per-row l2norm of q and k (rows of 32). q <- (q/||q|| + qe_h) * softplus(t_h)*ln(1024)
// k <- k/||k||. One 32-lane group per row, 8 rows per 256-thread block.
// ---------------------------------------------------------------------------
__global__ __launch_bounds__(256)
void norm_qk(float* __restrict__ q, float* __restrict__ k,
             const float* __restrict__ qe, const float* __restrict__ temp)
{
    int tid = threadIdx.x;
    int d = tid & 31;
    int row = blockIdx.x * 8 + (tid >> 5);   // 0..65535 over (b,h,n)
    int h = (row >> 10) & 7;
    size_t off = (size_t)row * 32 + d;
    float qv = q[off], kv = k[off];
    float qs = qv*qv, ks = kv*kv;
    #pragma unroll
    for (int m = 1; m <= 16; m <<= 1) {
        qs += __shfl_xor(qs, m);
        ks += __shfl_xor(ks, m);
    }
    float qn = qv / fmaxf(sqrtf(qs), 1e-12f);
    float kn = kv / fmaxf(sqrtf(ks), 1e-12f);
    float t = temp[h];
    float scale = log1pf(__expf(t)) * 6.9314718055994531f;  // softplus * ln(1024)
    q[off] = (qn + qe[h*32 + d]) * scale;
    k[off] = kn;
}

// ---------------------------------------------------------------------------
// Flash-style attention. Block = (b, h, 64-row Q tile). 256 threads (16x16).
// Bias table row for head h lives in LDS; bias gathered via rpi int4 loads.
// Online softmax across 16-lane row groups. P->LDS->PV. Output y in [B,N,H*32].
// ---------------------------------------------------------------------------
__global__ __launch_bounds__(256)
void attn_kernel(const float* __restrict__ qn, const float* __restrict__ kn,
                 const float* __restrict__ vv, const float* __restrict__ table,
                 const int* __restrict__ rpi, float* __restrict__ y)
{
    __shared__ __align__(16) float tbl[3969];
    __shared__ __align__(16) float Qs[64][36];
    __shared__ __align__(16) float Ks[64][36];
    __shared__ __align__(16) float Vs[64][36];
    __shared__ __align__(16) float Ps[64][68];

    int bh = blockIdx.x >> 4;     // b*8 + h
    int qt = blockIdx.x & 15;
    int h  = bh & 7;
    int b  = bh >> 3;
    int tid = threadIdx.x;
    int tx = tid & 15, ty = tid >> 4;

    for (int i = tid; i < 3969; i += 256) tbl[i] = table[h*3969 + i];

    const float* qbase = qn + ((size_t)bh*1024 + qt*64) * 32;
    #pragma unroll
    for (int i = 0; i < 2; ++i) {
        int e = tid + i*256;             // float4 index 0..511
        int r = e >> 3, c4 = (e & 7) * 4;
        *(float4*)&Qs[r][c4] = *(const float4*)(qbase + r*32 + c4);
    }

    float m_i[4], l_i[4], acc0[4], acc1[4];
    #pragma unroll
    for (int i = 0; i < 4; ++i) { m_i[i] = -1e30f; l_i[i] = 0.f; acc0[i] = 0.f; acc1[i] = 0.f; }
    int qr0 = qt*64 + ty*4;
    const int* rpibase = rpi + (size_t)qr0 * 1024;
    __syncthreads();

    for (int kt = 0; kt < 16; ++kt) {
        const float* kbase = kn + ((size_t)bh*1024 + kt*64) * 32;
        const float* vbase = vv + ((size_t)bh*1024 + kt*64) * 32;
        #pragma unroll
        for (int i = 0; i < 2; ++i) {
            int e = tid + i*256;
            int r = e >> 3, c4 = (e & 7) * 4;
            *(float4*)&Ks[r][c4] = *(const float4*)(kbase + r*32 + c4);
            *(float4*)&Vs[r][c4] = *(const float4*)(vbase + r*32 + c4);
        }
        __syncthreads();

        // S = Q K^T (4x4 per thread) + bias gather
        float s[4][4];
        #pragma unroll
        for (int i=0;i<4;i++) { s[i][0]=0.f; s[i][1]=0.f; s[i][2]=0.f; s[i][3]=0.f; }
        #pragma unroll
        for (int c4 = 0; c4 < 32; c4 += 4) {
            float4 a[4], bb4[4];
            #pragma unroll
            for (int i=0;i<4;i++) a[i]   = *(const float4*)&Qs[ty*4+i][c4];
            #pragma unroll
            for (int j=0;j<4;j++) bb4[j] = *(const float4*)&Ks[tx*4+j][c4];
            #pragma unroll
            for (int i=0;i<4;i++)
                #pragma unroll
                for (int j=0;j<4;j++)
                    s[i][j] += a[i].x*bb4[j].x + a[i].y*bb4[j].y + a[i].z*bb4[j].z + a[i].w*bb4[j].w;
        }
        #pragma unroll
        for (int i=0;i<4;i++) {
            int4 idx = *(const int4*)(rpibase + i*1024 + kt*64 + tx*4);
            s[i][0] += tbl[idx.x]; s[i][1] += tbl[idx.y];
            s[i][2] += tbl[idx.z]; s[i][3] += tbl[idx.w];
        }

        // online softmax per row (16-lane groups share a row set)
        #pragma unroll
        for (int i=0;i<4;i++) {
            float tm = fmaxf(fmaxf(s[i][0], s[i][1]), fmaxf(s[i][2], s[i][3]));
            tm = fmaxf(tm, __shfl_xor(tm, 1));
            tm = fmaxf(tm, __shfl_xor(tm, 2));
            tm = fmaxf(tm, __shfl_xor(tm, 4));
            tm = fmaxf(tm, __shfl_xor(tm, 8));
            float mn = fmaxf(m_i[i], tm);
            float alpha = __expf(m_i[i] - mn);
            float rs = 0.f;
            #pragma unroll
            for (int j=0;j<4;j++) { float p = __expf(s[i][j] - mn); s[i][j] = p; rs += p; }
            rs += __shfl_xor(rs, 1); rs += __shfl_xor(rs, 2);
            rs += __shfl_xor(rs, 4); rs += __shfl_xor(rs, 8);
            l_i[i] = l_i[i]*alpha + rs;
            m_i[i] = mn;
            acc0[i] *= alpha; acc1[i] *= alpha;
            *(float4*)&Ps[ty*4+i][tx*4] = make_float4(s[i][0], s[i][1], s[i][2], s[i][3]);
        }
        __syncthreads();

        // O += P @ V  (4 rows x 2 cols per thread; cols tx and tx+16)
        #pragma unroll
        for (int kk = 0; kk < 64; kk += 4) {
            float4 p4[4];
            #pragma unroll
            for (int i=0;i<4;i++) p4[i] = *(const float4*)&Ps[ty*4+i][kk];
            #pragma unroll
            for (int dd = 0; dd < 4; ++dd) {
                float v0 = Vs[kk+dd][tx];
                float v1 = Vs[kk+dd][tx+16];
                #pragma unroll
                for (int i=0;i<4;i++) {
                    float p = (dd==0)?p4[i].x:(dd==1)?p4[i].y:(dd==2)?p4[i].z:p4[i].w;
                    acc0[i] += p*v0;
                    acc1[i] += p*v1;
                }
            }
        }
        __syncthreads();
    }

    #pragma unroll
    for (int i=0;i<4;i++) {
        float inv = 1.0f / l_i[i];
        int qr = qr0 + i;
        size_t base = ((size_t)b*1024 + qr)*256 + h*32;
        y[base + tx]      = acc0[i]*inv;
        y[base + tx + 16] = acc1[i]*inv;
    }
}

// ---------------------------------------------------------------------------
extern "C" void kernel_launch(void* const* d_in, const int* in_sizes, int n_in,
                              void* d_out, int out_size, void* d_ws, size_t ws_size,
                              hipStream_t stream)
{
    const float* x     = (const float*)d_in[0];
    // d_in[1] = H, d_in[2] = W (unused scalars)
    const int*   rpi   = (const int*)d_in[3];
    const float* rct   = (const float*)d_in[4];
    const float* qkvw  = (const float*)d_in[5];
    const float* qkvb  = (const float*)d_in[6];
    const float* qe    = (const float*)d_in[7];
    const float* temp  = (const float*)d_in[8];
    const float* projw = (const float*)d_in[9];
    const float* projb = (const float*)d_in[10];
    const float* fc1w  = (const float*)d_in[11];
    const float* fc1b  = (const float*)d_in[12];
    const float* fc2w  = (const float*)d_in[13];
    const float* fc2b  = (const float*)d_in[14];

    float* ws  = (float*)d_ws;
    float* qb  = ws;
    float* kb  = ws + (size_t)QSZ;
    float* vb  = ws + (size_t)2*QSZ;
    float* y   = ws + (size_t)3*QSZ;
    float* tbl = ws + (size_t)4*QSZ;
    float* out = (float*)d_out;

    // 1) CPB MLP -> bias table [8][3969]
    cpb_kernel<<<16, 256, 0, stream>>>(rct, fc1w, fc1b, fc2w, fc2b, tbl);

    // 2) QKV GEMM with scatter into q/k/v [B,H,N,32]
    dim3 g1(768/64, 8192/64);
    sgemm_bt<1><<<g1, 256, 0, stream>>>(x, qkvw, qkvb, nullptr, qb, kb, vb, 8192, 768, 256);

    // 3) l2norm + query-embedding + temperature scale
    norm_qk<<<8192, 256, 0, stream>>>(qb, kb, qe, temp);

    // 4) attention -> y [B,N,256]
    attn_kernel<<<1024, 256, 0, stream>>>(qb, kb, vb, tbl, rpi, y);

    // 5) output projection -> d_out
    dim3 g2(256/64, 8192/64);
    sgemm_bt<0><<<g2, 256, 0, stream>>>(y, projw, projb, out, nullptr, nullptr, nullptr, 8192, 256, 256);
}

// Round 2
// 305.254 us; speedup vs baseline: 1.7657x; 1.7657x over previous
//
#include <hip/hip_runtime.h>
#include <hip/hip_bf16.h>
#include <cstddef>

// Problem constants
#define QSZ 2097152  // B*H*N*HD = 8*8*1024*32 floats (also = 8192*256)

typedef float v4f __attribute__((ext_vector_type(4)));
typedef short v8s __attribute__((ext_vector_type(8)));

__device__ inline short f2bf(float x) {
    __hip_bfloat16 h = __float2bfloat16(x);
    short s; __builtin_memcpy(&s, &h, 2); return s;
}
__device__ inline float bf2f(short s) {
    __hip_bfloat16 h; __builtin_memcpy(&h, &s, 2);
    return __bfloat162float(h);
}

// ---------------------------------------------------------------------------
// CPB MLP: table[h][r] = fc2(relu(fc1(rct[r]))) ; one thread per table row.
// ---------------------------------------------------------------------------
__global__ __launch_bounds__(256)
void cpb_kernel(const float* __restrict__ rct,
                const float* __restrict__ fc1w, const float* __restrict__ fc1b,
                const float* __restrict__ fc2w, const float* __restrict__ fc2b,
                float* __restrict__ table)
{
    int r = blockIdx.x * 256 + threadIdx.x;
    if (r >= 3969) return;
    float c0 = rct[2*r], c1 = rct[2*r+1];
    float acc[8] = {0,0,0,0,0,0,0,0};
    for (int j = 0; j < 512; ++j) {
        float hv = fmaxf(c0*fc1w[2*j] + c1*fc1w[2*j+1] + fc1b[j], 0.0f);
        #pragma unroll
        for (int hh = 0; hh < 8; ++hh) acc[hh] += hv * fc2w[hh*512 + j];
    }
    #pragma unroll
    for (int hh = 0; hh < 8; ++hh) table[hh*3969 + r] = acc[hh] + fc2b[hh];
}

// ---------------------------------------------------------------------------
// Tiled fp32 SGEMM, C[m][n] = sum_k A[m][k]*W[n][k] + bias[n]
// MODE 0: plain row-major C. MODE 1: scatter qkv channels into q/k/v [B,H,N,32].
// ---------------------------------------------------------------------------
template<int MODE>
__global__ __launch_bounds__(256)
void sgemm_bt(const float* __restrict__ A, const float* __restrict__ W,
              const float* __restrict__ bias, float* __restrict__ C,
              float* __restrict__ qb, float* __restrict__ kb, float* __restrict__ vb,
              int M, int N, int K)
{
    __shared__ __align__(16) float As[16][68];
    __shared__ __align__(16) float Bs[16][68];
    int tid = threadIdx.x;
    int tx = tid & 15, ty = tid >> 4;
    int m0 = blockIdx.y * 64, n0 = blockIdx.x * 64;
    int lm = tid >> 2;          // 0..63
    int lk = (tid & 3) * 4;     // 0,4,8,12
    float acc[4][4] = {};
    const float* Ap = A + (size_t)(m0 + lm) * K + lk;
    const float* Wp = W + (size_t)(n0 + lm) * K + lk;

    for (int k0 = 0; k0 < K; k0 += 16) {
        float4 a4 = *(const float4*)(Ap + k0);
        float4 w4 = *(const float4*)(Wp + k0);
        As[lk+0][lm]=a4.x; As[lk+1][lm]=a4.y; As[lk+2][lm]=a4.z; As[lk+3][lm]=a4.w;
        Bs[lk+0][lm]=w4.x; Bs[lk+1][lm]=w4.y; Bs[lk+2][lm]=w4.z; Bs[lk+3][lm]=w4.w;
        __syncthreads();
        #pragma unroll
        for (int kk = 0; kk < 16; ++kk) {
            float4 av = *(const float4*)&As[kk][ty*4];
            float4 bv = *(const float4*)&Bs[kk][tx*4];
            float aa[4] = {av.x, av.y, av.z, av.w};
            float bb[4] = {bv.x, bv.y, bv.z, bv.w};
            #pragma unroll
            for (int i = 0; i < 4; ++i)
                #pragma unroll
                for (int j = 0; j < 4; ++j)
                    acc[i][j] += aa[i] * bb[j];
        }
        __syncthreads();
    }

    if (MODE == 0) {
        #pragma unroll
        for (int i = 0; i < 4; ++i) {
            int m = m0 + ty*4 + i;
            int n = n0 + tx*4;
            float4 o;
            o.x = acc[i][0] + bias[n+0];
            o.y = acc[i][1] + bias[n+1];
            o.z = acc[i][2] + bias[n+2];
            o.w = acc[i][3] + bias[n+3];
            *(float4*)(C + (size_t)m*N + n) = o;
        }
    } else {
        int n = n0 + tx*4;
        int which = n >> 8;
        int head  = (n >> 5) & 7;
        int dd    = n & 31;
        float* dst = (which == 0) ? qb : (which == 1) ? kb : vb;
        #pragma unroll
        for (int i = 0; i < 4; ++i) {
            int m = m0 + ty*4 + i;
            int bb = m >> 10, nrow = m & 1023;
            float4 o;
            o.x = acc[i][0] + bias[n+0];
            o.y = acc[i][1] + bias[n+1];
            o.z = acc[i][2] + bias[n+2];
            o.w = acc[i][3] + bias[n+3];
            *(float4*)(dst + (((size_t)bb*8 + head)*1024 + nrow)*32 + dd) = o;
        }
    }
}

// ---------------------------------------------------------------------------
// Per-row l2norm of q and k. q <- (q/||q|| + qe_h) * softplus(t_h)*ln(1024)
// ---------------------------------------------------------------------------
__global__ __launch_bounds__(256)
void norm_qk(float* __restrict__ q, float* __restrict__ k,
             const float* __restrict__ qe, const float* __restrict__ temp)
{
    int tid = threadIdx.x;
    int d = tid & 31;
    int row = blockIdx.x * 8 + (tid >> 5);
    int h = (row >> 10) & 7;
    size_t off = (size_t)row * 32 + d;
    float qv = q[off], kv = k[off];
    float qs = qv*qv, ks = kv*kv;
    #pragma unroll
    for (int m = 1; m <= 16; m <<= 1) {
        qs += __shfl_xor(qs, m);
        ks += __shfl_xor(ks, m);
    }
    float qn = qv / fmaxf(sqrtf(qs), 1e-12f);
    float kn = kv / fmaxf(sqrtf(ks), 1e-12f);
    float t = temp[h];
    float scale = log1pf(__expf(t)) * 6.9314718055994531f;
    q[off] = (qn + qe[h*32 + d]) * scale;
    k[off] = kn;
}

// ---------------------------------------------------------------------------
// MFMA flash attention. Block = (b,h,64-row Q tile), 4 waves, wave = 16 Q rows.
// S via split-bf16 (hi+lo) 3-pass MFMA => ~fp32-accurate logits.
// P (bf16) -> LDS -> A-frag; V staged transposed [dim][key] bf16.
// mfma_f32_16x16x32_bf16 layouts (verified):
//   A: A[m=lane&15][k=quad*8+j] ; B: Bt[n=lane&15][k=quad*8+j] (Bt=B^T rows)
//   C/D: row m = quad*4+reg, col n = lane&15
// ---------------------------------------------------------------------------
__global__ __launch_bounds__(256)
void attn_mfma(const float* __restrict__ qn, const float* __restrict__ kn,
               const float* __restrict__ vv, const float* __restrict__ table,
               const int* __restrict__ rpi, float* __restrict__ y)
{
    __shared__ __align__(16) short tbl[3970];       // bf16 bias table   7940 B
    __shared__ __align__(16) short Khi[64][40];     // K hi, pad->80B row 5120 B
    __shared__ __align__(16) short Klo[64][40];     // K lo              5120 B
    __shared__ __align__(16) short Vt[32][88];      // V^T [dim][key]    5632 B
    __shared__ __align__(16) short Ps[4][16][88];   // P per wave       11264 B

    int bh  = blockIdx.x >> 4;
    int qt  = blockIdx.x & 15;
    int h   = bh & 7;
    int b   = bh >> 3;
    int tid = threadIdx.x;
    int w    = tid >> 6;        // wave 0..3
    int lane = tid & 63;
    int t    = lane & 15;       // n / m lane index
    int quad = lane >> 4;

    for (int i = tid; i < 3969; i += 256) tbl[i] = f2bf(table[h*3969 + i]);

    // Q A-fragments (hi/lo), held in registers for the whole kernel
    const float* qbase = qn + ((size_t)bh*1024 + qt*64 + w*16) * 32;
    float4 qa = *(const float4*)(qbase + t*32 + quad*8);
    float4 qb4 = *(const float4*)(qbase + t*32 + quad*8 + 4);
    float qvals[8] = {qa.x,qa.y,qa.z,qa.w,qb4.x,qb4.y,qb4.z,qb4.w};
    v8s qhi, qlo;
    #pragma unroll
    for (int j = 0; j < 8; ++j) {
        short hi = f2bf(qvals[j]);
        qhi[j] = hi;
        qlo[j] = f2bf(qvals[j] - bf2f(hi));
    }

    v4f Oacc[2] = {{0,0,0,0},{0,0,0,0}};
    float m_i[4] = {-1e30f,-1e30f,-1e30f,-1e30f};
    float l_i[4] = {0,0,0,0};

    int kr = tid >> 2;            // staging: key row 0..63
    int c0 = (tid & 3) * 8;       // staging: dim chunk 0,8,16,24
    const float* kst = kn + (size_t)bh*1024*32;
    const float* vst = vv + (size_t)bh*1024*32;
    int qrow0 = qt*64 + w*16 + quad*4;   // first of this lane's 4 S rows

    for (int kt = 0; kt < 16; ++kt) {
        __syncthreads();   // prior tile's LDS reads done before overwrite
        // ---- stage K (hi/lo) and V^T for this 64-key tile ----
        const float* kp = kst + (size_t)(kt*64 + kr)*32 + c0;
        float4 k0 = *(const float4*)kp;
        float4 k1 = *(const float4*)(kp + 4);
        const float* vp = vst + (size_t)(kt*64 + kr)*32 + c0;
        float4 v0 = *(const float4*)vp;
        float4 v1 = *(const float4*)(vp + 4);
        float kvals[8] = {k0.x,k0.y,k0.z,k0.w,k1.x,k1.y,k1.z,k1.w};
        float vvals[8] = {v0.x,v0.y,v0.z,v0.w,v1.x,v1.y,v1.z,v1.w};
        v8s khi8, klo8;
        #pragma unroll
        for (int j = 0; j < 8; ++j) {
            short hi = f2bf(kvals[j]);
            khi8[j] = hi;
            klo8[j] = f2bf(kvals[j] - bf2f(hi));
        }
        *(v8s*)&Khi[kr][c0] = khi8;
        *(v8s*)&Klo[kr][c0] = klo8;
        #pragma unroll
        for (int j = 0; j < 8; ++j) Vt[c0+j][kr] = f2bf(vvals[j]);
        __syncthreads();

        // ---- S = Q K^T over 4 n-groups of 16 keys, split-bf16 3 passes ----
        v4f S[4];
        #pragma unroll
        for (int g = 0; g < 4; ++g) {
            v8s bhi = *(const v8s*)&Khi[g*16 + t][quad*8];
            v8s blo = *(const v8s*)&Klo[g*16 + t][quad*8];
            v4f c = {0,0,0,0};
            c = __builtin_amdgcn_mfma_f32_16x16x32_bf16(qhi, bhi, c, 0, 0, 0);
            c = __builtin_amdgcn_mfma_f32_16x16x32_bf16(qlo, bhi, c, 0, 0, 0);
            c = __builtin_amdgcn_mfma_f32_16x16x32_bf16(qhi, blo, c, 0, 0, 0);
            S[g] = c;
        }

        // ---- relative-position bias gather ----
        #pragma unroll
        for (int r = 0; r < 4; ++r) {
            const int* rr = rpi + (size_t)(qrow0 + r)*1024 + kt*64 + t;
            #pragma unroll
            for (int g = 0; g < 4; ++g)
                S[g][r] += bf2f(tbl[rr[g*16]]);
        }

        // ---- online softmax (row = quad*4+r, 16 lanes share a row) ----
        #pragma unroll
        for (int r = 0; r < 4; ++r) {
            float tm = fmaxf(fmaxf(S[0][r], S[1][r]), fmaxf(S[2][r], S[3][r]));
            tm = fmaxf(tm, __shfl_xor(tm, 1));
            tm = fmaxf(tm, __shfl_xor(tm, 2));
            tm = fmaxf(tm, __shfl_xor(tm, 4));
            tm = fmaxf(tm, __shfl_xor(tm, 8));
            float mn = fmaxf(m_i[r], tm);
            float al = __expf(m_i[r] - mn);
            float rs = 0.f;
            #pragma unroll
            for (int g = 0; g < 4; ++g) {
                float p = __expf(S[g][r] - mn);
                S[g][r] = p;
                rs += p;
            }
            rs += __shfl_xor(rs, 1); rs += __shfl_xor(rs, 2);
            rs += __shfl_xor(rs, 4); rs += __shfl_xor(rs, 8);
            l_i[r] = l_i[r]*al + rs;
            m_i[r] = mn;
            Oacc[0][r] *= al;
            Oacc[1][r] *= al;
            int prow = quad*4 + r;
            #pragma unroll
            for (int g = 0; g < 4; ++g)
                Ps[w][prow][g*16 + t] = f2bf(S[g][r]);
        }
        __syncthreads();   // P write -> P read (and keeps waves aligned)

        // ---- O += P V ----
        #pragma unroll
        for (int ks = 0; ks < 2; ++ks) {
            v8s pf = *(const v8s*)&Ps[w][t][ks*32 + quad*8];
            #pragma unroll
            for (int g = 0; g < 2; ++g) {
                v8s vf = *(const v8s*)&Vt[g*16 + t][ks*32 + quad*8];
                Oacc[g] = __builtin_amdgcn_mfma_f32_16x16x32_bf16(pf, vf, Oacc[g], 0, 0, 0);
            }
        }
    }

    // ---- epilogue: normalize, write y [B,N,256] ----
    #pragma unroll
    for (int r = 0; r < 4; ++r) {
        float inv = 1.0f / l_i[r];
        int qrow = qrow0 + r;
        size_t base = ((size_t)b*1024 + qrow)*256 + h*32;
        y[base + t]      = Oacc[0][r] * inv;
        y[base + 16 + t] = Oacc[1][r] * inv;
    }
}

// ---------------------------------------------------------------------------
extern "C" void kernel_launch(void* const* d_in, const int* in_sizes, int n_in,
                              void* d_out, int out_size, void* d_ws, size_t ws_size,
                              hipStream_t stream)
{
    const float* x     = (const float*)d_in[0];
    const int*   rpi   = (const int*)d_in[3];
    const float* rct   = (const float*)d_in[4];
    const float* qkvw  = (const float*)d_in[5];
    const float* qkvb  = (const float*)d_in[6];
    const float* qe    = (const float*)d_in[7];
    const float* temp  = (const float*)d_in[8];
    const float* projw = (const float*)d_in[9];
    const float* projb = (const float*)d_in[10];
    const float* fc1w  = (const float*)d_in[11];
    const float* fc1b  = (const float*)d_in[12];
    const float* fc2w  = (const float*)d_in[13];
    const float* fc2b  = (const float*)d_in[14];

    float* ws  = (float*)d_ws;
    float* qb  = ws;
    float* kb  = ws + (size_t)QSZ;
    float* vb  = ws + (size_t)2*QSZ;
    float* y   = ws + (size_t)3*QSZ;
    float* tbl = ws + (size_t)4*QSZ;
    float* out = (float*)d_out;

    // 1) CPB MLP -> bias table [8][3969]
    cpb_kernel<<<16, 256, 0, stream>>>(rct, fc1w, fc1b, fc2w, fc2b, tbl);

    // 2) QKV GEMM with scatter into q/k/v [B,H,N,32]
    dim3 g1(768/64, 8192/64);
    sgemm_bt<1><<<g1, 256, 0, stream>>>(x, qkvw, qkvb, nullptr, qb, kb, vb, 8192, 768, 256);

    // 3) l2norm + query-embedding + temperature scale
    norm_qk<<<8192, 256, 0, stream>>>(qb, kb, qe, temp);

    // 4) MFMA attention -> y [B,N,256]
    attn_mfma<<<1024, 256, 0, stream>>>(qb, kb, vb, tbl, rpi, y);

    // 5) output projection -> d_out
    dim3 g2(256/64, 8192/64);
    sgemm_bt<0><<<g2, 256, 0, stream>>>(y, projw, projb, out, nullptr, nullptr, nullptr, 8192, 256, 256);
}

// Round 3
// 192.216 us; speedup vs baseline: 2.8041x; 1.5881x over previous
//
#include <hip/hip_runtime.h>
#include <hip/hip_bf16.h>
#include <cstddef>
#include <cstdint>

typedef float v4f __attribute__((ext_vector_type(4)));
typedef short v8s __attribute__((ext_vector_type(8)));

__device__ __forceinline__ short f2bf(float x) {
    __hip_bfloat16 h = __float2bfloat16(x);
    short s; __builtin_memcpy(&s, &h, 2); return s;
}
__device__ __forceinline__ float bf2f(short s) {
    __hip_bfloat16 h; __builtin_memcpy(&h, &s, 2);
    return __bfloat162float(h);
}
__device__ __forceinline__ void gld16(const void* g, void* l) {
    __builtin_amdgcn_global_load_lds(
        (const __attribute__((address_space(1))) unsigned int*)g,
        (__attribute__((address_space(3))) unsigned int*)l, 16, 0, 0);
}
#define MFMA(a,b,c) __builtin_amdgcn_mfma_f32_16x16x32_bf16((a),(b),(c),0,0,0)

// ---------------------------------------------------------------------------
// CPB MLP with LDS-staged weights: table[h][r] = fc2(relu(fc1(rct[r])))
// ---------------------------------------------------------------------------
__global__ __launch_bounds__(256)
void cpb_kernel(const float* __restrict__ rct,
                const float* __restrict__ fc1w, const float* __restrict__ fc1b,
                const float* __restrict__ fc2w, const float* __restrict__ fc2b,
                float* __restrict__ table)
{
    __shared__ float s1[1024];
    __shared__ float sb[512];
    __shared__ float s2[4096];
    int tid = threadIdx.x;
    for (int i = tid; i < 1024; i += 256) s1[i] = fc1w[i];
    for (int i = tid; i < 512;  i += 256) sb[i] = fc1b[i];
    for (int i = tid; i < 4096; i += 256) s2[i] = fc2w[i];
    __syncthreads();
    int r = blockIdx.x * 256 + tid;
    bool ok = r < 3969;
    float c0 = ok ? rct[2*r]   : 0.f;
    float c1 = ok ? rct[2*r+1] : 0.f;
    float a[8] = {0,0,0,0,0,0,0,0};
    for (int j = 0; j < 512; ++j) {
        float hv = fmaxf(c0*s1[2*j] + c1*s1[2*j+1] + sb[j], 0.0f);
        #pragma unroll
        for (int hh = 0; hh < 8; ++hh) a[hh] += hv * s2[hh*512 + j];
    }
    if (ok) {
        #pragma unroll
        for (int hh = 0; hh < 8; ++hh) table[hh*3969 + r] = a[hh] + fc2b[hh];
    }
}

// ---------------------------------------------------------------------------
// Split fp32 -> bf16 hi/lo, stored 16B-chunk-swizzled for LDS-conflict-free
// frag reads: chunk c of row m stored at chunk (c ^ (m&7)) within its 64-elem
// K-tile. All arrays have inner dim K=256. x:1024 blocks, wq:96, wp:32.
// ---------------------------------------------------------------------------
__global__ __launch_bounds__(256)
void split_kernel(const float* __restrict__ x,  short* __restrict__ xh,  short* __restrict__ xl,
                  const float* __restrict__ wq, short* __restrict__ wqh, short* __restrict__ wql,
                  const float* __restrict__ wp, short* __restrict__ wph, short* __restrict__ wpl)
{
    int bid = blockIdx.x;
    const float* src; short* dh; short* dl; int base8;
    if (bid < 1024)      { src = x;  dh = xh;  dl = xl;  base8 = bid * 256; }
    else if (bid < 1120) { src = wq; dh = wqh; dl = wql; base8 = (bid-1024) * 256; }
    else                 { src = wp; dh = wph; dl = wpl; base8 = (bid-1120) * 256; }
    int e0 = (base8 + (int)threadIdx.x) * 8;
    int m  = e0 >> 8;
    int k  = e0 & 255;
    int kt = k >> 6, c = (k >> 3) & 7;
    float4 f0 = *(const float4*)(src + e0);
    float4 f1 = *(const float4*)(src + e0 + 4);
    float v[8] = {f0.x,f0.y,f0.z,f0.w,f1.x,f1.y,f1.z,f1.w};
    v8s hi, lo;
    #pragma unroll
    for (int j = 0; j < 8; ++j) {
        short h = f2bf(v[j]);
        hi[j] = h;
        lo[j] = f2bf(v[j] - bf2f(h));
    }
    int dst = m*256 + kt*64 + ((c ^ (m & 7)) << 3);
    *(v8s*)&dh[dst] = hi;
    *(v8s*)&dl[dst] = lo;
}

// ---------------------------------------------------------------------------
// Split-bf16 MFMA GEMM: C = A(MxK=256) * W(NxK=256)^T + bias, 3-pass hi/lo.
// TM=128, TN=64, BK=64, 256 threads = 4 waves (2x2 wave grid).
// MODE 0: plain fp32 C [M][N].
// MODE 1: qkv epilogue — q: l2norm + qe + softplus(temp)*ln(1024), split hi/lo;
//         k: l2norm, split hi/lo (chunk-swizzled); v: bf16 transposed to
//         vt[bh][32][1024] (64-key-tile chunk-swizzled) via LDS.
// ---------------------------------------------------------------------------
template<int MODE>
__global__ __launch_bounds__(256)
void gemm_mfma(const short* __restrict__ Ahi, const short* __restrict__ Alo,
               const short* __restrict__ Whi, const short* __restrict__ Wlo,
               const float* __restrict__ bias, float* __restrict__ C,
               short* __restrict__ qhi, short* __restrict__ qlo,
               short* __restrict__ khi, short* __restrict__ klo,
               short* __restrict__ vt,
               const float* __restrict__ qe, const float* __restrict__ temp,
               int N)
{
    __shared__ __align__(16) char smem[49152];
    short* Ah = (short*)smem;          // [128][64]
    short* Al = Ah + 128*64;
    short* Wh = Al + 128*64;           // [64][64]
    short* Wl = Wh + 64*64;

    int tid  = threadIdx.x;
    int w    = tid >> 6;
    int lane = tid & 63;
    int t    = lane & 15;
    int quad = lane >> 4;
    int m0 = blockIdx.y * 128, n0 = blockIdx.x * 64;
    int Mw = (w >> 1) * 64, Nw = (w & 1) * 32;

    v4f acc[4][2];
    #pragma unroll
    for (int mt = 0; mt < 4; ++mt)
        #pragma unroll
        for (int nt = 0; nt < 2; ++nt) acc[mt][nt] = (v4f){0,0,0,0};

    int lr8 = lane >> 3, lc8 = lane & 7;
    #pragma unroll 1
    for (int kt = 0; kt < 4; ++kt) {
        __syncthreads();
        #pragma unroll
        for (int i = 0; i < 4; ++i) {
            size_t grow = (size_t)(m0 + w*32 + i*8 + lr8) * 256 + kt*64 + lc8*8;
            int ls = (w*32 + i*8) * 64;
            gld16(Ahi + grow, Ah + ls);
            gld16(Alo + grow, Al + ls);
        }
        #pragma unroll
        for (int i = 0; i < 2; ++i) {
            size_t grow = (size_t)(n0 + w*16 + i*8 + lr8) * 256 + kt*64 + lc8*8;
            int ls = (w*16 + i*8) * 64;
            gld16(Whi + grow, Wh + ls);
            gld16(Wlo + grow, Wl + ls);
        }
        __syncthreads();
        #pragma unroll
        for (int kk = 0; kk < 2; ++kk) {
            int cp = ((kk*4 + quad) ^ (t & 7)) << 3;
            v8s bh8[2], bl8[2];
            #pragma unroll
            for (int nt = 0; nt < 2; ++nt) {
                int rowi = Nw + nt*16 + t;
                bh8[nt] = *(const v8s*)&Wh[rowi*64 + cp];
                bl8[nt] = *(const v8s*)&Wl[rowi*64 + cp];
            }
            #pragma unroll
            for (int mt = 0; mt < 4; ++mt) {
                int rowi = Mw + mt*16 + t;
                v8s ah = *(const v8s*)&Ah[rowi*64 + cp];
                v8s al = *(const v8s*)&Al[rowi*64 + cp];
                #pragma unroll
                for (int nt = 0; nt < 2; ++nt) {
                    acc[mt][nt] = MFMA(ah, bh8[nt], acc[mt][nt]);
                    acc[mt][nt] = MFMA(al, bh8[nt], acc[mt][nt]);
                    acc[mt][nt] = MFMA(ah, bl8[nt], acc[mt][nt]);
                }
            }
        }
    }

    // bias
    #pragma unroll
    for (int nt = 0; nt < 2; ++nt) {
        float bv = bias[n0 + Nw + nt*16 + t];
        #pragma unroll
        for (int mt = 0; mt < 4; ++mt)
            #pragma unroll
            for (int r = 0; r < 4; ++r) acc[mt][nt][r] += bv;
    }

    if (MODE == 0) {
        #pragma unroll
        for (int mt = 0; mt < 4; ++mt)
            #pragma unroll
            for (int r = 0; r < 4; ++r) {
                int m = m0 + Mw + mt*16 + quad*4 + r;
                #pragma unroll
                for (int nt = 0; nt < 2; ++nt) {
                    int n = n0 + Nw + nt*16 + t;
                    C[(size_t)m * N + n] = acc[mt][nt][r];
                }
            }
    } else {
        int which = n0 >> 8;                 // block-uniform (q/k/v bands are 256 wide)
        if (which < 2) {
            int head = ((n0 + Nw) >> 5) & 7; // wave-uniform
            float scale = 0.f;
            if (which == 0)
                scale = log1pf(__expf(temp[head])) * 6.9314718055994531f;
            #pragma unroll
            for (int mt = 0; mt < 4; ++mt)
                #pragma unroll
                for (int r = 0; r < 4; ++r) {
                    float a0 = acc[mt][0][r], a1 = acc[mt][1][r];
                    float s = a0*a0 + a1*a1;
                    s += __shfl_xor(s, 1); s += __shfl_xor(s, 2);
                    s += __shfl_xor(s, 4); s += __shfl_xor(s, 8);
                    float inv = 1.0f / fmaxf(sqrtf(s), 1e-12f);
                    int m = m0 + Mw + mt*16 + quad*4 + r;
                    int b = m >> 10, nrow = m & 1023;
                    size_t rowoff = (((size_t)b*8 + head)*1024 + nrow) * 32;
                    int swk = (nrow >> 1) & 3;
                    #pragma unroll
                    for (int nt = 0; nt < 2; ++nt) {
                        int d = nt*16 + t;
                        float val = acc[mt][nt][r] * inv;
                        if (which == 0) {
                            val = (val + qe[head*32 + d]) * scale;
                            short hb = f2bf(val);
                            qhi[rowoff + d] = hb;
                            qlo[rowoff + d] = f2bf(val - bf2f(hb));
                        } else {
                            int c = d >> 3;
                            int dpos = ((c ^ swk) << 3) | (d & 7);
                            short hb = f2bf(val);
                            khi[rowoff + dpos] = hb;
                            klo[rowoff + dpos] = f2bf(val - bf2f(hb));
                        }
                    }
                }
        } else {
            // v: transpose via LDS, write vt[bh][dim][key] bf16, tile-swizzled
            __syncthreads();                 // staging LDS reads done in all waves
            short* VT = (short*)smem;        // [64][136]
            #pragma unroll
            for (int mt = 0; mt < 4; ++mt)
                #pragma unroll
                for (int nt = 0; nt < 2; ++nt) {
                    int cl = Nw + nt*16 + t;
                    #pragma unroll
                    for (int r = 0; r < 4; ++r) {
                        int rl = Mw + mt*16 + quad*4 + r;
                        VT[cl*136 + rl] = f2bf(acc[mt][nt][r]);
                    }
                }
            __syncthreads();
            int b = m0 >> 10;
            int keybase = m0 & 1023;
            int headbase = ((n0 - 512) >> 5) & 7;
            int cl = tid >> 2;
            int dim = cl & 31;
            int hd  = headbase + (cl >> 5);
            size_t obase = (((size_t)b*8 + hd)*32 + dim) * 1024 + keybase;
            #pragma unroll
            for (int p = 0; p < 4; ++p) {
                int ci  = (tid & 3) * 4 + p;     // 0..15
                int ktl = ci >> 3, c = ci & 7;
                v8s val = *(const v8s*)&VT[cl*136 + ktl*64 + c*8];
                *(v8s*)&vt[obase + ktl*64 + ((c ^ (dim & 7)) << 3)] = val;
            }
        }
    }
}

// ---------------------------------------------------------------------------
// MFMA flash attention, fixed-max softmax (logits bounded by ~36 < 40).
// Block = (b,h,64-row Q tile), 4 waves x 16 Q rows. Staging via
// global_load_lds from pre-split/pre-swizzled khi/klo/vt. Output: swizzled
// bf16 hi/lo y for the proj GEMM.
// ---------------------------------------------------------------------------
__global__ __launch_bounds__(256)
void attn_mfma(const short* __restrict__ qhi, const short* __restrict__ qlo,
               const short* __restrict__ khi, const short* __restrict__ klo,
               const short* __restrict__ vt,  const float* __restrict__ tblf,
               const int* __restrict__ rpi,
               short* __restrict__ yhi, short* __restrict__ ylo)
{
    __shared__ __align__(16) short tbl[3970];
    __shared__ __align__(16) short Khi_s[2048];   // [64][32]
    __shared__ __align__(16) short Klo_s[2048];
    __shared__ __align__(16) short Vt_s[2048];    // [32][64]
    __shared__ __align__(16) short Ps[4][16][88];

    int bh  = blockIdx.x >> 4;
    int qt  = blockIdx.x & 15;
    int h   = bh & 7;
    int b   = bh >> 3;
    int tid = threadIdx.x;
    int w    = tid >> 6;
    int lane = tid & 63;
    int t    = lane & 15;
    int quad = lane >> 4;

    for (int i = tid; i < 3969; i += 256) tbl[i] = f2bf(tblf[h*3969 + i]);

    // Q fragments from global (plain layout)
    size_t qoff = ((size_t)bh*1024 + qt*64 + w*16 + t) * 32 + quad*8;
    v8s qfh = *(const v8s*)(qhi + qoff);
    v8s qfl = *(const v8s*)(qlo + qoff);

    v4f Oacc[2] = {{0,0,0,0},{0,0,0,0}};
    float lsum[4] = {0,0,0,0};

    size_t kgbase = (size_t)bh * 32768;
    int qrow0 = qt*64 + w*16 + quad*4;
    const int* rpibase = rpi + (size_t)qrow0 * 1024;
    int swzS = (quad ^ ((t >> 1) & 3)) << 3;
    int lr8 = lane >> 3, lc8 = lane & 7;

    #pragma unroll 1
    for (int kt = 0; kt < 16; ++kt) {
        __syncthreads();
        // stage K hi/lo (64x32) and V^T (32x64): 3 async 1KB loads per wave
        gld16(khi + kgbase + (size_t)kt*2048 + w*512 + lane*8, &Khi_s[w*512]);
        gld16(klo + kgbase + (size_t)kt*2048 + w*512 + lane*8, &Klo_s[w*512]);
        gld16(vt + kgbase + (size_t)(w*8 + lr8)*1024 + kt*64 + lc8*8, &Vt_s[w*512]);
        __syncthreads();

        // S = Q K^T, split-bf16 3 passes
        v4f S[4];
        #pragma unroll
        for (int g = 0; g < 4; ++g) {
            const short* kb = &Khi_s[(g*16 + t)*32];
            const short* kl2 = &Klo_s[(g*16 + t)*32];
            v8s bh8 = *(const v8s*)(kb + swzS);
            v8s bl8 = *(const v8s*)(kl2 + swzS);
            v4f c = {0,0,0,0};
            c = MFMA(qfh, bh8, c);
            c = MFMA(qfl, bh8, c);
            c = MFMA(qfh, bl8, c);
            S[g] = c;
        }

        // relative-position bias
        #pragma unroll
        for (int r = 0; r < 4; ++r) {
            const int* rr = rpibase + (size_t)r*1024 + kt*64 + t;
            #pragma unroll
            for (int g = 0; g < 4; ++g)
                S[g][r] += bf2f(tbl[rr[g*16]]);
        }

        // fixed-max softmax: p = exp(S - 40), per-lane partial l
        #pragma unroll
        for (int r = 0; r < 4; ++r) {
            int prow = quad*4 + r;
            #pragma unroll
            for (int g = 0; g < 4; ++g) {
                float p = __expf(S[g][r] - 40.0f);
                lsum[r] += p;
                Ps[w][prow][g*16 + t] = f2bf(p);
            }
        }
        // O += P V (per-wave LDS, no barrier needed: same-wave dependency)
        #pragma unroll
        for (int ks = 0; ks < 2; ++ks) {
            v8s pf = *(const v8s*)&Ps[w][t][ks*32 + quad*8];
            int vsw = ((ks*4 + quad) ^ (t & 7)) << 3;
            #pragma unroll
            for (int g = 0; g < 2; ++g) {
                v8s vf = *(const v8s*)(&Vt_s[(g*16 + t)*64] + vsw);
                Oacc[g] = MFMA(pf, vf, Oacc[g]);
            }
        }
    }

    // epilogue: reduce l across the 16 key-lanes, normalize, write swizzled y
    #pragma unroll
    for (int r = 0; r < 4; ++r) {
        float l = lsum[r];
        l += __shfl_xor(l, 1); l += __shfl_xor(l, 2);
        l += __shfl_xor(l, 4); l += __shfl_xor(l, 8);
        float inv = 1.0f / l;
        int qrow = qrow0 + r;
        int m = b*1024 + qrow;
        size_t mbase = (size_t)m * 256;
        int mk = m & 7;
        #pragma unroll
        for (int g = 0; g < 2; ++g) {
            float o = Oacc[g][r] * inv;
            int c = h*4 + g*2 + (t >> 3);
            int chp = ((c ^ mk) << 3) | (t & 7);
            short hb = f2bf(o);
            yhi[mbase + chp] = hb;
            ylo[mbase + chp] = f2bf(o - bf2f(hb));
        }
    }
}

// ---------------------------------------------------------------------------
extern "C" void kernel_launch(void* const* d_in, const int* in_sizes, int n_in,
                              void* d_out, int out_size, void* d_ws, size_t ws_size,
                              hipStream_t stream)
{
    const float* x     = (const float*)d_in[0];
    const int*   rpi   = (const int*)d_in[3];
    const float* rct   = (const float*)d_in[4];
    const float* qkvw  = (const float*)d_in[5];
    const float* qkvb  = (const float*)d_in[6];
    const float* qe    = (const float*)d_in[7];
    const float* temp  = (const float*)d_in[8];
    const float* projw = (const float*)d_in[9];
    const float* projb = (const float*)d_in[10];
    const float* fc1w  = (const float*)d_in[11];
    const float* fc1b  = (const float*)d_in[12];
    const float* fc2w  = (const float*)d_in[13];
    const float* fc2b  = (const float*)d_in[14];

    char* p = (char*)d_ws;
    float* tblf = (float*)p;  p += 131072;
    short* xh   = (short*)p;  p += 4194304;   // reused as yhi after QKV GEMM
    short* xl   = (short*)p;  p += 4194304;   // reused as ylo
    short* wqh  = (short*)p;  p += 393216;
    short* wql  = (short*)p;  p += 393216;
    short* wph  = (short*)p;  p += 131072;
    short* wpl  = (short*)p;  p += 131072;
    short* qh   = (short*)p;  p += 4194304;
    short* ql   = (short*)p;  p += 4194304;
    short* kh   = (short*)p;  p += 4194304;
    short* kl   = (short*)p;  p += 4194304;
    short* vt   = (short*)p;  p += 4194304;
    float* out  = (float*)d_out;

    // 1) CPB MLP -> fp32 bias table [8][3969]
    cpb_kernel<<<16, 256, 0, stream>>>(rct, fc1w, fc1b, fc2w, fc2b, tblf);

    // 2) split x / qkv_w / proj_w into swizzled bf16 hi/lo
    split_kernel<<<1152, 256, 0, stream>>>(x, xh, xl, qkvw, wqh, wql, projw, wph, wpl);

    // 3) QKV GEMM + fused l2norm/scale/split + V transpose
    dim3 g1(768/64, 8192/128);
    gemm_mfma<1><<<g1, 256, 0, stream>>>(xh, xl, wqh, wql, qkvb, nullptr,
                                         qh, ql, kh, kl, vt, qe, temp, 768);

    // 4) MFMA attention -> swizzled bf16 hi/lo y (aliases xh/xl)
    attn_mfma<<<1024, 256, 0, stream>>>(qh, ql, kh, kl, vt, tblf, rpi, xh, xl);

    // 5) output projection -> d_out (fp32)
    dim3 g2(256/64, 8192/128);
    gemm_mfma<0><<<g2, 256, 0, stream>>>(xh, xl, wph, wpl, projb, out,
                                         nullptr, nullptr, nullptr, nullptr,
                                         nullptr, nullptr, nullptr, 256);
}